// Round 7
// baseline (825.081 us; speedup 1.0000x reference)
//
#include <hip/hip_runtime.h>
#include <hip/hip_bf16.h>
#include <math.h>

#define N_NODES 100000
#define R_REL 3
#define E_EDGES 320000
#define HID 128
#define HD 128
#define NBLK 391        // ceil(N/256)
#define GBLK 782        // ceil(N/128)

// ---------------- workspace layout (byte offsets) ----------------
static constexpr size_t OFF_EXCSR = 0;                     // R*E*4 f32 = 15,360,000
static constexpr size_t OFF_WTS_T = 16000000;              // R*128*128 bf16 = 98,304
static constexpr size_t OFF_WG_T  = 16098304;              // R*128*128 bf16 = 98,304
static constexpr size_t OFF_W1_T  = 16196608;              // 128*128 bf16 = 32,768
static constexpr size_t OFF_MER   = 16229376;              // R*128*4 f32 = 6,144
static constexpr size_t OFF_CER   = 16235520;              // R*4 f32 = 48 -> 64
static constexpr size_t OFF_PART  = 16235584;              // R*GBLK f32 = 9,384
static constexpr size_t OFF_B1    = 51200000;              // z_r: R*N*128 f32
static constexpr size_t OFF_B2    = 204800000;             // hs: R*N*128 f32
static constexpr size_t OFF_EL    = 358400000;             // R*N*4 f32
static constexpr size_t OFF_ER    = 363200000;             // R*N*4 f32
static constexpr size_t OFF_CNT   = 368006144;             // R*N i32
static constexpr size_t OFF_OFFS  = 369206144;             // R*(N+1) i32
static constexpr size_t OFF_CUR   = 370406272;             // R*N i32
static constexpr size_t OFF_BSUM  = 371606272;             // R*NBLK i32
static constexpr size_t OFF_BOFF  = 371611136;             // R*NBLK i32
static constexpr size_t OFF_CSR   = 371616000;             // R*E i32
static constexpr size_t OFF_ABUF  = 375456000;             // 3 f32

typedef __attribute__((ext_vector_type(8))) short short8;
typedef __attribute__((ext_vector_type(4))) float floatx4;

__device__ __forceinline__ unsigned f2bf(float f)
{
    unsigned u = __float_as_uint(f);
    return (u + 0x7FFFu + ((u >> 16) & 1u)) >> 16;   // RNE
}

__device__ __forceinline__ float fast_tanh(float x)
{
    x = fminf(fmaxf(x, -15.0f), 15.0f);
    float e = __expf(2.0f * x);
    return (e - 1.0f) / (e + 1.0f);
}

// ---------------- weight pre-transpose: dst[n][k] = bf16(src[k][n]) ----------------
__global__ void transpose_bf16(const float* __restrict__ src, unsigned short* __restrict__ dst)
{
    int mat = blockIdx.y;
    int idx = blockIdx.x * 256 + threadIdx.x;   // 64 blocks x 256 = 16384
    int n = idx >> 7, k = idx & 127;
    dst[(size_t)mat * 16384 + n * 128 + k] =
        (unsigned short)f2bf(src[(size_t)mat * 16384 + k * 128 + n]);
}

// ---------------- er prep: wr_eff = reduce(Wg,attn_r); M = Wt_dst@wr_eff; c = bt_dst@wr_eff ----
__global__ __launch_bounds__(512) void prep_er(const float* __restrict__ Wg,
                                               const float* __restrict__ attn_r,
                                               const float* __restrict__ Wt_dst,
                                               const float* __restrict__ bt_dst,
                                               float* __restrict__ M, float* __restrict__ cvec)
{
    const int r = blockIdx.x;
    const int t = threadIdx.x;          // 512 = 128 f x 4 h
    const int f = t >> 2, h = t & 3;
    __shared__ float wr[128][4];
    float s = 0.0f;
#pragma unroll
    for (int d = 0; d < 32; ++d)
        s += Wg[(size_t)r * 16384 + f * 128 + h * 32 + d] * attn_r[r * 128 + h * 32 + d];
    wr[f][h] = s;
    __syncthreads();
    float m = 0.0f;
    for (int k = 0; k < 128; ++k) m += Wt_dst[f * 128 + k] * wr[k][h];
    M[((size_t)r * 128 + f) * 4 + h] = m;
    if (f == 0) {
        float c = 0.0f;
        for (int k = 0; k < 128; ++k) c += bt_dst[k] * wr[k][h];
        cvec[r * 4 + h] = c;
    }
}

// ---------------- er_direct: er[r][n][h] = dst_feat[n,:]·M[r][:,h] + c[r][h] ----------------
__global__ __launch_bounds__(256) void er_direct(const float* __restrict__ dst_feat,
                                                 const float* __restrict__ M,
                                                 const float* __restrict__ cvec,
                                                 float* __restrict__ er)
{
    int n = blockIdx.x * 4 + (threadIdx.x >> 6);
    int lane = threadIdx.x & 63;
    float d0 = dst_feat[(size_t)n * 128 + lane];
    float d1 = dst_feat[(size_t)n * 128 + 64 + lane];
#pragma unroll
    for (int r = 0; r < R_REL; ++r) {
        float4 w0 = *(const float4*)(M + ((size_t)r * 128 + lane) * 4);
        float4 w1 = *(const float4*)(M + ((size_t)r * 128 + 64 + lane) * 4);
        float p0 = d0 * w0.x + d1 * w1.x;
        float p1 = d0 * w0.y + d1 * w1.y;
        float p2 = d0 * w0.z + d1 * w1.z;
        float p3 = d0 * w0.w + d1 * w1.w;
#pragma unroll
        for (int off = 32; off >= 1; off >>= 1) {
            p0 += __shfl_down(p0, off);
            p1 += __shfl_down(p1, off);
            p2 += __shfl_down(p2, off);
            p3 += __shfl_down(p3, off);
        }
        if (lane == 0) {
            float4 c4 = *(const float4*)(cvec + r * 4);
            float4 o = { p0 + c4.x, p1 + c4.y, p2 + c4.z, p3 + c4.w };
            *(float4*)(er + ((size_t)r * N_NODES + n) * 4) = o;
        }
    }
}

// ---------------- fused src pipeline v4: 8 waves x (64x32), low-VGPR, B streamed per kc -----
#define XPITCH 136   // ushorts/row = 272B: 16B-aligned, dword stride 68 == 4 (mod 32) (conflict-free class)
__global__ __launch_bounds__(512) void fused_src_kernel(
    const float* __restrict__ src_feats, const unsigned short* __restrict__ WtsT,
    const float* __restrict__ bt_src, const unsigned short* __restrict__ WgT,
    const float* __restrict__ attn_l, float* __restrict__ hs, float* __restrict__ el)
{
    __shared__ unsigned short Xs[128 * XPITCH];   // 34.8 KB: input tile, then srcT tile
    const int r = blockIdx.y;
    const int row0 = blockIdx.x * 128;
    const int t = threadIdx.x, wave = t >> 6, lane = t & 63;
    const int wm = wave >> 2, wc = wave & 3, lm = lane & 15, quad = lane >> 4;
    const float* A = src_feats + (size_t)r * N_NODES * 128;

    // stage input tile fp32->bf16 (8 float4 per thread)
#pragma unroll
    for (int i = 0; i < 8; ++i) {
        int item = t + i * 512;                 // 4096 = 128 rows x 32 float4
        int m = item >> 5, kq = item & 31;
        int gr = row0 + m; gr = gr < N_NODES ? gr : N_NODES - 1;
        float4 v = *(const float4*)(A + (size_t)gr * 128 + kq * 4);
        uint2 u;
        u.x = f2bf(v.x) | (f2bf(v.y) << 16);
        u.y = f2bf(v.z) | (f2bf(v.w) << 16);
        *(uint2*)(&Xs[m * XPITCH + kq * 4]) = u;
    }
    __syncthreads();

    floatx4 acc[4][2];
#pragma unroll
    for (int i = 0; i < 4; ++i)
#pragma unroll
        for (int j = 0; j < 2; ++j) acc[i][j] = (floatx4){0.f, 0.f, 0.f, 0.f};

    // GEMM1: srcT tile = input @ Wt_src^T  (B streamed from L2 per kc)
    const unsigned short* B1 = WtsT + r * 16384;
#pragma unroll
    for (int kc = 0; kc < 4; ++kc) {
        short8 bk[2];
#pragma unroll
        for (int nt = 0; nt < 2; ++nt)
            bk[nt] = *(const short8*)(B1 + (wc * 32 + nt * 16 + lm) * 128 + kc * 32 + quad * 8);
        short8 af[4];
#pragma unroll
        for (int mt = 0; mt < 4; ++mt)
            af[mt] = *(const short8*)(&Xs[(wm * 64 + mt * 16 + lm) * XPITCH + kc * 32 + quad * 8]);
#pragma unroll
        for (int mt = 0; mt < 4; ++mt)
#pragma unroll
            for (int nt = 0; nt < 2; ++nt)
                acc[mt][nt] = __builtin_amdgcn_mfma_f32_16x16x32_bf16(af[mt], bk[nt], acc[mt][nt], 0, 0, 0);
    }
    __syncthreads();   // all Xs (input) reads done

    // repack srcT (+bias) -> bf16 -> Xs (pair-packed via shfl_xor: 4B aligned writes)
#pragma unroll
    for (int mt = 0; mt < 4; ++mt) {
#pragma unroll
        for (int nt = 0; nt < 2; ++nt) {
            const int col = wc * 32 + nt * 16 + lm;
            const float bv = bt_src[r * 128 + col];
#pragma unroll
            for (int rg = 0; rg < 4; ++rg) {
                unsigned mb = f2bf(acc[mt][nt][rg] + bv);
                unsigned pb = (unsigned)__shfl_xor((int)mb, 1);
                if ((lm & 1) == 0) {
                    int trow = wm * 64 + mt * 16 + quad * 4 + rg;
                    *(unsigned*)(&Xs[trow * XPITCH + col]) = mb | (pb << 16);
                }
            }
        }
    }
    __syncthreads();

#pragma unroll
    for (int i = 0; i < 4; ++i)
#pragma unroll
        for (int j = 0; j < 2; ++j) acc[i][j] = (floatx4){0.f, 0.f, 0.f, 0.f};

    // GEMM2: hs tile = srcT @ Wg^T
    const unsigned short* B2 = WgT + r * 16384;
#pragma unroll
    for (int kc = 0; kc < 4; ++kc) {
        short8 bk[2];
#pragma unroll
        for (int nt = 0; nt < 2; ++nt)
            bk[nt] = *(const short8*)(B2 + (wc * 32 + nt * 16 + lm) * 128 + kc * 32 + quad * 8);
        short8 af[4];
#pragma unroll
        for (int mt = 0; mt < 4; ++mt)
            af[mt] = *(const short8*)(&Xs[(wm * 64 + mt * 16 + lm) * XPITCH + kc * 32 + quad * 8]);
#pragma unroll
        for (int mt = 0; mt < 4; ++mt)
#pragma unroll
            for (int nt = 0; nt < 2; ++nt)
                acc[mt][nt] = __builtin_amdgcn_mfma_f32_16x16x32_bf16(af[mt], bk[nt], acc[mt][nt], 0, 0, 0);
    }

    // epilogue: write hs + el[row][head]; this wave's 32 cols == head wc
    const float* alr = attn_l + r * 128;
    float* hsr = hs + (size_t)r * N_NODES * 128;
    float* elr = el + (size_t)r * N_NODES * 4;
#pragma unroll
    for (int mt = 0; mt < 4; ++mt) {
        float e4[4] = {0.f, 0.f, 0.f, 0.f};
#pragma unroll
        for (int nt = 0; nt < 2; ++nt) {
            const int col = wc * 32 + nt * 16 + lm;
            const float al = alr[col];
#pragma unroll
            for (int rg = 0; rg < 4; ++rg) {
                int gr = row0 + wm * 64 + mt * 16 + quad * 4 + rg;
                float v = acc[mt][nt][rg];
                if (gr < N_NODES) hsr[(size_t)gr * 128 + col] = v;
                e4[rg] += v * al;
            }
        }
#pragma unroll
        for (int rg = 0; rg < 4; ++rg) {
            float a = e4[rg];
            a += __shfl_down(a, 8);
            a += __shfl_down(a, 4);
            a += __shfl_down(a, 2);
            a += __shfl_down(a, 1);
            if (lm == 0) {
                int gr = row0 + wm * 64 + mt * 16 + quad * 4 + rg;
                if (gr < N_NODES) elr[(size_t)gr * 4 + wc] = a;
            }
        }
    }
}

// ---------------- fused semantic: T=zr@W1+b1 (regs only) -> partial of sum(tanh(T)*W2) --------
__global__ __launch_bounds__(256) void fused_sem_kernel(
    const float* __restrict__ zr, const unsigned short* __restrict__ W1T,
    const float* __restrict__ b1, const float* __restrict__ W2,
    float* __restrict__ partials)
{
    __shared__ unsigned short Xs[128 * XPITCH];
    const int r = blockIdx.y;
    const int row0 = blockIdx.x * 128;
    const int t = threadIdx.x, wave = t >> 6, lane = t & 63;
    const int wm = wave >> 1, wn = wave & 1, lm = lane & 15, quad = lane >> 4;
    const float* A = zr + (size_t)r * N_NODES * 128;

#pragma unroll
    for (int i = 0; i < 16; ++i) {
        int item = t + i * 256;
        int m = item >> 5, kq = item & 31;
        int gr = row0 + m; gr = gr < N_NODES ? gr : N_NODES - 1;
        float4 v = *(const float4*)(A + (size_t)gr * 128 + kq * 4);
        uint2 u;
        u.x = f2bf(v.x) | (f2bf(v.y) << 16);
        u.y = f2bf(v.z) | (f2bf(v.w) << 16);
        *(uint2*)(&Xs[m * XPITCH + kq * 4]) = u;
    }
    short8 bfrag[4][4];
#pragma unroll
    for (int nt = 0; nt < 4; ++nt)
#pragma unroll
        for (int kc = 0; kc < 4; ++kc)
            bfrag[nt][kc] = *(const short8*)(W1T + (wn * 64 + nt * 16 + lm) * 128 + kc * 32 + quad * 8);
    __syncthreads();

    floatx4 acc[4][4];
#pragma unroll
    for (int i = 0; i < 4; ++i)
#pragma unroll
        for (int j = 0; j < 4; ++j) acc[i][j] = (floatx4){0.f, 0.f, 0.f, 0.f};
#pragma unroll
    for (int kc = 0; kc < 4; ++kc) {
        short8 af[4];
#pragma unroll
        for (int mt = 0; mt < 4; ++mt)
            af[mt] = *(const short8*)(&Xs[(wm * 64 + mt * 16 + lm) * XPITCH + kc * 32 + quad * 8]);
#pragma unroll
        for (int mt = 0; mt < 4; ++mt)
#pragma unroll
            for (int nt = 0; nt < 4; ++nt)
                acc[mt][nt] = __builtin_amdgcn_mfma_f32_16x16x32_bf16(af[mt], bfrag[nt][kc], acc[mt][nt], 0, 0, 0);
    }

    float s = 0.0f;
#pragma unroll
    for (int nt = 0; nt < 4; ++nt) {
        const int col = wn * 64 + nt * 16 + lm;
        const float w2v = W2[col];
        const float b1v = b1[col];
#pragma unroll
        for (int mt = 0; mt < 4; ++mt)
#pragma unroll
            for (int rg = 0; rg < 4; ++rg) {
                int gr = row0 + wm * 64 + mt * 16 + quad * 4 + rg;
                if (gr < N_NODES) s += fast_tanh(acc[mt][nt][rg] + b1v) * w2v;
            }
    }
#pragma unroll
    for (int off = 32; off >= 1; off >>= 1) s += __shfl_down(s, off);
    __shared__ float ws4[4];
    if (lane == 0) ws4[wave] = s;
    __syncthreads();
    if (t == 0) partials[r * GBLK + blockIdx.x] = ws4[0] + ws4[1] + ws4[2] + ws4[3];
}

// ---------------- CSR build ----------------
__global__ void count_kernel(const int* __restrict__ dst_idx, int* __restrict__ counts)
{
    int tid = blockIdx.x * 256 + threadIdx.x;
    if (tid >= R_REL * E_EDGES) return;
    int r = tid / E_EDGES;
    atomicAdd(&counts[r * N_NODES + dst_idx[tid]], 1);
}

__global__ void blocksum_kernel(const int* __restrict__ counts, int* __restrict__ bsums)
{
    int r = blockIdx.y;
    int i = blockIdx.x * 256 + threadIdx.x;
    int v = (i < N_NODES) ? counts[r * N_NODES + i] : 0;
#pragma unroll
    for (int off = 32; off >= 1; off >>= 1) v += __shfl_down(v, off);
    __shared__ int wsum[4];
    int lane = threadIdx.x & 63, w = threadIdx.x >> 6;
    if (lane == 0) wsum[w] = v;
    __syncthreads();
    if (threadIdx.x == 0) bsums[r * NBLK + blockIdx.x] = wsum[0] + wsum[1] + wsum[2] + wsum[3];
}

__global__ void scan_bsums(const int* __restrict__ bsums, int* __restrict__ boffs,
                           int* __restrict__ offs)
{
    int r = blockIdx.x;
    if (threadIdx.x != 0) return;
    int run = 0;
    for (int b = 0; b < NBLK; ++b) { boffs[r * NBLK + b] = run; run += bsums[r * NBLK + b]; }
    offs[r * (N_NODES + 1) + N_NODES] = run;
}

__global__ void scan_final(const int* __restrict__ counts, const int* __restrict__ boffs,
                           int* __restrict__ offs, int* __restrict__ cursor)
{
    int r = blockIdx.y;
    int i = blockIdx.x * 256 + threadIdx.x;
    int t = threadIdx.x;
    int v = (i < N_NODES) ? counts[r * N_NODES + i] : 0;
    __shared__ int sd[256];
    sd[t] = v;
    __syncthreads();
    for (int off = 1; off < 256; off <<= 1) {
        int y = (t >= off) ? sd[t - off] : 0;
        __syncthreads();
        sd[t] += y;
        __syncthreads();
    }
    int excl = sd[t] - v + boffs[r * NBLK + blockIdx.x];
    if (i < N_NODES) {
        offs[r * (N_NODES + 1) + i] = excl;
        cursor[r * N_NODES + i] = excl;
    }
}

// scatter + fused edge logits (softmax shift-invariance: no max subtraction needed, logits O(1))
__global__ void scatter_ex(const int* __restrict__ src_idx, const int* __restrict__ dst_idx,
                           const float* __restrict__ el, const float* __restrict__ er,
                           int* __restrict__ cursor, int* __restrict__ csr_src,
                           float* __restrict__ ex_csr)
{
    int tid = blockIdx.x * 256 + threadIdx.x;
    if (tid >= R_REL * E_EDGES) return;
    int r = tid / E_EDGES;
    int s = src_idx[tid], d = dst_idx[tid];
    float4 a = *(const float4*)(el + ((size_t)r * N_NODES + s) * 4);
    float4 b = *(const float4*)(er + ((size_t)r * N_NODES + d) * 4);
    float e0 = a.x + b.x, e1 = a.y + b.y, e2 = a.z + b.z, e3 = a.w + b.w;
    e0 = e0 > 0.f ? e0 : 0.2f * e0;
    e1 = e1 > 0.f ? e1 : 0.2f * e1;
    e2 = e2 > 0.f ? e2 : 0.2f * e2;
    e3 = e3 > 0.f ? e3 : 0.2f * e3;
    float4 ex = { __expf(e0), __expf(e1), __expf(e2), __expf(e3) };
    int pos = atomicAdd(&cursor[r * N_NODES + d], 1);
    csr_src[(size_t)r * E_EDGES + pos] = s;
    *(float4*)(ex_csr + ((size_t)r * E_EDGES + pos) * 4) = ex;
}

// ---------------- node-centric aggregation v3: K=8 predicated batch issue ------------------
// Post-mortem R6: v2's per-pair index loads serialized the index->gather chain (BW fell
// 2.86->2.48 TB/s at identical traffic). v3 keeps broadcast loads (no shuffle VALU) but
// restores batched MLP: 8 clamped index loads issued together, 8 ex loads together, then
// 16 gathers together -> 2 serial memory round-trips per node instead of ~2 per edge.
// P(deg>8) ~ 0.6% (Poisson 3.2) so the outer loop almost never repeats. All arrays fully
// unrolled (compile-time indices -> registers).
__global__ __launch_bounds__(256) void agg_kernel(
    const float* __restrict__ ex_csr, const float* __restrict__ hs,
    const int* __restrict__ offs, const int* __restrict__ csr_src,
    const float* __restrict__ bias_g, float* __restrict__ zr)
{
    int wid = blockIdx.x * 4 + (threadIdx.x >> 6);
    int r = wid / N_NODES, n = wid - r * N_NODES;
    int lane = threadIdx.x & 63;
    int h0 = lane >> 5;
    int c0 = lane, c1 = lane + 64;

    int beg = offs[r * (N_NODES + 1) + n];
    int end = offs[r * (N_NODES + 1) + n + 1];
    const int*   srcs = csr_src + (size_t)r * E_EDGES;
    const float* exc  = ex_csr + (size_t)r * E_EDGES * 4;
    const float* hsr  = hs + (size_t)r * N_NODES * HD;

    float ss0 = 0.f, ss1 = 0.f, acc0 = 0.f, acc1 = 0.f;
    for (int base = beg; base < end; base += 8) {
        int idx[8];
        float4 ev[8];
        // batch 1: all index loads issued back-to-back (clamped; one vmcnt wait)
#pragma unroll
        for (int k = 0; k < 8; ++k) {
            int jj = base + k; jj = jj < end ? jj : base;
            idx[k] = srcs[jj];
        }
        // batch 2: all ex loads issued back-to-back
#pragma unroll
        for (int k = 0; k < 8; ++k) {
            int jj = base + k; jj = jj < end ? jj : base;
            ev[k] = *(const float4*)(exc + (size_t)jj * 4);
        }
        // batch 3: 16 gathers issued back-to-back (invalid slots re-read edge-0 row: L1 hit)
        float g0[8], g1[8];
#pragma unroll
        for (int k = 0; k < 8; ++k) {
            g0[k] = hsr[(size_t)idx[k] * HD + c0];
            g1[k] = hsr[(size_t)idx[k] * HD + c1];
        }
        // accumulate (invalid slots zeroed via ev)
#pragma unroll
        for (int k = 0; k < 8; ++k) {
            bool v = (base + k) < end;
            float e0 = h0 ? ev[k].y : ev[k].x;
            float e1 = h0 ? ev[k].w : ev[k].z;
            e0 = v ? e0 : 0.f;
            e1 = v ? e1 : 0.f;
            ss0 += e0;
            ss1 += e1;
            acc0 += e0 * g0[k];
            acc1 += e1 * g1[k];
        }
    }
    float r0 = acc0 / (ss0 + 1e-9f) + bias_g[r * HD + c0];
    float r1 = acc1 / (ss1 + 1e-9f) + bias_g[r * HD + c1];
    r0 = r0 > 0.0f ? r0 : (__expf(r0) - 1.0f);
    r1 = r1 > 0.0f ? r1 : (__expf(r1) - 1.0f);
    zr[(size_t)wid * HD + c0] = r0;
    zr[(size_t)wid * HD + c1] = r1;
}

// ---------------- final softmax over relations + combine ----------------
__global__ __launch_bounds__(256) void softmax_a(const float* __restrict__ partials,
                                                 float* __restrict__ a,
                                                 float* __restrict__ out)
{
    __shared__ float sm[3];
    const int t = threadIdx.x;
    if (t < 192) {
        const int r = t >> 6, lane = t & 63;
        float v = 0.0f;
        for (int i = lane; i < GBLK; i += 64) v += partials[r * GBLK + i];
#pragma unroll
        for (int off = 32; off >= 1; off >>= 1) v += __shfl_down(v, off);
        if (lane == 0) sm[r] = v;
    }
    __syncthreads();
    if (t == 0) {
        float w0 = sm[0] / (float)N_NODES;
        float w1 = sm[1] / (float)N_NODES;
        float w2 = sm[2] / (float)N_NODES;
        float m = fmaxf(w0, fmaxf(w1, w2));
        float e0 = __expf(w0 - m), e1 = __expf(w1 - m), e2 = __expf(w2 - m);
        float s = e0 + e1 + e2;
        a[0] = e0 / s; a[1] = e1 / s; a[2] = e2 / s;
        out[(size_t)N_NODES * HD + 0] = a[0];
        out[(size_t)N_NODES * HD + 1] = a[1];
        out[(size_t)N_NODES * HD + 2] = a[2];
    }
}

__global__ __launch_bounds__(256) void combine_kernel(const float* __restrict__ zr,
                                                      const float* __restrict__ a,
                                                      float* __restrict__ out)
{
    size_t i = (size_t)blockIdx.x * 256 + threadIdx.x;
    float a0 = a[0], a1 = a[1], a2 = a[2];
    const float4 v0 = ((const float4*)zr)[i];
    const float4 v1 = ((const float4*)(zr + (size_t)N_NODES * HD))[i];
    const float4 v2 = ((const float4*)(zr + 2 * (size_t)N_NODES * HD))[i];
    float4 o = { a0 * v0.x + a1 * v1.x + a2 * v2.x,
                 a0 * v0.y + a1 * v1.y + a2 * v2.y,
                 a0 * v0.z + a1 * v1.z + a2 * v2.z,
                 a0 * v0.w + a1 * v1.w + a2 * v2.w };
    ((float4*)out)[i] = o;
}

// ---------------- launch ----------------
extern "C" void kernel_launch(void* const* d_in, const int* in_sizes, int n_in,
                              void* d_out, int out_size, void* d_ws, size_t ws_size,
                              hipStream_t stream)
{
    const float* dst_feat  = (const float*)d_in[0];
    const float* src_feats = (const float*)d_in[1];
    const int*   src_idx   = (const int*)d_in[2];
    const int*   dst_idx   = (const int*)d_in[3];
    const float* Wt_dst    = (const float*)d_in[4];
    const float* bt_dst    = (const float*)d_in[5];
    const float* Wt_src    = (const float*)d_in[6];
    const float* bt_src    = (const float*)d_in[7];
    const float* Wg        = (const float*)d_in[8];
    const float* attn_l    = (const float*)d_in[9];
    const float* attn_r    = (const float*)d_in[10];
    const float* bias_g    = (const float*)d_in[11];
    const float* W1        = (const float*)d_in[12];
    const float* b1        = (const float*)d_in[13];
    const float* W2        = (const float*)d_in[14];
    float* out = (float*)d_out;

    char* ws = (char*)d_ws;
    float*          ex_csr = (float*)(ws + OFF_EXCSR);
    unsigned short* WtsT   = (unsigned short*)(ws + OFF_WTS_T);
    unsigned short* WgT    = (unsigned short*)(ws + OFF_WG_T);
    unsigned short* W1T    = (unsigned short*)(ws + OFF_W1_T);
    float*          Mer    = (float*)(ws + OFF_MER);
    float*          cer    = (float*)(ws + OFF_CER);
    float*          parts  = (float*)(ws + OFF_PART);
    float*          zr     = (float*)(ws + OFF_B1);
    float*          hs     = (float*)(ws + OFF_B2);
    float*          el     = (float*)(ws + OFF_EL);
    float*          er     = (float*)(ws + OFF_ER);
    int*            counts = (int*)(ws + OFF_CNT);
    int*            offs   = (int*)(ws + OFF_OFFS);
    int*            cursor = (int*)(ws + OFF_CUR);
    int*            bsums  = (int*)(ws + OFF_BSUM);
    int*            boffs  = (int*)(ws + OFF_BOFF);
    int*            csr    = (int*)(ws + OFF_CSR);
    float*          abuf   = (float*)(ws + OFF_ABUF);

    hipMemsetAsync(counts, 0, (size_t)R_REL * N_NODES * 4, stream);

    // prep: weight transposes (bf16 [n][k]) + er projection matrix
    transpose_bf16<<<dim3(64, 3), 256, 0, stream>>>(Wt_src, WtsT);
    transpose_bf16<<<dim3(64, 3), 256, 0, stream>>>(Wg, WgT);
    transpose_bf16<<<dim3(64, 1), 256, 0, stream>>>(W1, W1T);
    prep_er<<<3, 512, 0, stream>>>(Wg, attn_r, Wt_dst, bt_dst, Mer, cer);

    // fused src projection chain: hs + el (srcT never touches HBM)
    fused_src_kernel<<<dim3(GBLK, 3), 512, 0, stream>>>(src_feats, WtsT, bt_src, WgT,
                                                        attn_l, hs, el);
    // er directly from dst_feat
    er_direct<<<25000, 256, 0, stream>>>(dst_feat, Mer, cer, er);

    // CSR by dst
    count_kernel<<<3750, 256, 0, stream>>>(dst_idx, counts);
    blocksum_kernel<<<dim3(NBLK, 3), 256, 0, stream>>>(counts, bsums);
    scan_bsums<<<3, 64, 0, stream>>>(bsums, boffs, offs);
    scan_final<<<dim3(NBLK, 3), 256, 0, stream>>>(counts, boffs, offs, cursor);
    scatter_ex<<<3750, 256, 0, stream>>>(src_idx, dst_idx, el, er, cursor, csr, ex_csr);

    // pull aggregation -> zr
    agg_kernel<<<75000, 256, 0, stream>>>(ex_csr, hs, offs, csr, bias_g, zr);

    // fused semantic attention (T never materialized)
    fused_sem_kernel<<<dim3(GBLK, 3), 256, 0, stream>>>(zr, W1T, b1, W2, parts);
    softmax_a<<<1, 256, 0, stream>>>(parts, abuf, out);
    combine_kernel<<<12500, 256, 0, stream>>>(zr, abuf, out);
}

// Round 8
// 728.937 us; speedup vs baseline: 1.1319x; 1.1319x over previous
//
#include <hip/hip_runtime.h>
#include <hip/hip_bf16.h>
#include <math.h>

#define N_NODES 100000
#define R_REL 3
#define E_EDGES 320000
#define HID 128
#define HD 128
#define NBLK 391        // ceil(N/256)
#define GBLK 782        // ceil(N/128)

// ---------------- workspace layout (byte offsets) ----------------
static constexpr size_t OFF_EXCSR = 0;                     // R*E*4 f32 = 15,360,000
static constexpr size_t OFF_WTS_T = 16000000;              // R*128*128 bf16 = 98,304
static constexpr size_t OFF_WG_T  = 16098304;              // R*128*128 bf16 = 98,304
static constexpr size_t OFF_W1_T  = 16196608;              // 128*128 bf16 = 32,768
static constexpr size_t OFF_MER   = 16229376;              // R*128*4 f32 = 6,144
static constexpr size_t OFF_CER   = 16235520;              // R*4 f32 = 48 -> 64
static constexpr size_t OFF_PART  = 16235584;              // R*GBLK f32 = 9,384
static constexpr size_t OFF_B1    = 51200000;              // z_r: R*N*128 f32
static constexpr size_t OFF_B2    = 204800000;             // hs: R*N*128 bf16 (76.8 MB)
static constexpr size_t OFF_EL    = 358400000;             // R*N*4 f32
static constexpr size_t OFF_ER    = 363200000;             // R*N*4 f32
static constexpr size_t OFF_CNT   = 368006144;             // R*N i32
static constexpr size_t OFF_OFFS  = 369206144;             // R*(N+1) i32
static constexpr size_t OFF_CUR   = 370406272;             // R*N i32
static constexpr size_t OFF_BSUM  = 371606272;             // R*NBLK i32
static constexpr size_t OFF_BOFF  = 371611136;             // R*NBLK i32
static constexpr size_t OFF_CSR   = 371616000;             // R*E i32
static constexpr size_t OFF_ABUF  = 375456000;             // 3 f32

typedef __attribute__((ext_vector_type(8))) short short8;
typedef __attribute__((ext_vector_type(4))) float floatx4;

__device__ __forceinline__ unsigned f2bf(float f)
{
    unsigned u = __float_as_uint(f);
    return (u + 0x7FFFu + ((u >> 16) & 1u)) >> 16;   // RNE
}

__device__ __forceinline__ float fast_tanh(float x)
{
    x = fminf(fmaxf(x, -15.0f), 15.0f);
    float e = __expf(2.0f * x);
    return (e - 1.0f) / (e + 1.0f);
}

// ---------------- weight pre-transpose: dst[n][k] = bf16(src[k][n]) ----------------
__global__ void transpose_bf16(const float* __restrict__ src, unsigned short* __restrict__ dst)
{
    int mat = blockIdx.y;
    int idx = blockIdx.x * 256 + threadIdx.x;   // 64 blocks x 256 = 16384
    int n = idx >> 7, k = idx & 127;
    dst[(size_t)mat * 16384 + n * 128 + k] =
        (unsigned short)f2bf(src[(size_t)mat * 16384 + k * 128 + n]);
}

// ---------------- er prep: wr_eff = reduce(Wg,attn_r); M = Wt_dst@wr_eff; c = bt_dst@wr_eff ----
__global__ __launch_bounds__(512) void prep_er(const float* __restrict__ Wg,
                                               const float* __restrict__ attn_r,
                                               const float* __restrict__ Wt_dst,
                                               const float* __restrict__ bt_dst,
                                               float* __restrict__ M, float* __restrict__ cvec)
{
    const int r = blockIdx.x;
    const int t = threadIdx.x;          // 512 = 128 f x 4 h
    const int f = t >> 2, h = t & 3;
    __shared__ float wr[128][4];
    float s = 0.0f;
#pragma unroll
    for (int d = 0; d < 32; ++d)
        s += Wg[(size_t)r * 16384 + f * 128 + h * 32 + d] * attn_r[r * 128 + h * 32 + d];
    wr[f][h] = s;
    __syncthreads();
    float m = 0.0f;
    for (int k = 0; k < 128; ++k) m += Wt_dst[f * 128 + k] * wr[k][h];
    M[((size_t)r * 128 + f) * 4 + h] = m;
    if (f == 0) {
        float c = 0.0f;
        for (int k = 0; k < 128; ++k) c += bt_dst[k] * wr[k][h];
        cvec[r * 4 + h] = c;
    }
}

// ---------------- er_direct: er[r][n][h] = dst_feat[n,:]·M[r][:,h] + c[r][h] ----------------
__global__ __launch_bounds__(256) void er_direct(const float* __restrict__ dst_feat,
                                                 const float* __restrict__ M,
                                                 const float* __restrict__ cvec,
                                                 float* __restrict__ er)
{
    int n = blockIdx.x * 4 + (threadIdx.x >> 6);
    int lane = threadIdx.x & 63;
    float d0 = dst_feat[(size_t)n * 128 + lane];
    float d1 = dst_feat[(size_t)n * 128 + 64 + lane];
#pragma unroll
    for (int r = 0; r < R_REL; ++r) {
        float4 w0 = *(const float4*)(M + ((size_t)r * 128 + lane) * 4);
        float4 w1 = *(const float4*)(M + ((size_t)r * 128 + 64 + lane) * 4);
        float p0 = d0 * w0.x + d1 * w1.x;
        float p1 = d0 * w0.y + d1 * w1.y;
        float p2 = d0 * w0.z + d1 * w1.z;
        float p3 = d0 * w0.w + d1 * w1.w;
#pragma unroll
        for (int off = 32; off >= 1; off >>= 1) {
            p0 += __shfl_down(p0, off);
            p1 += __shfl_down(p1, off);
            p2 += __shfl_down(p2, off);
            p3 += __shfl_down(p3, off);
        }
        if (lane == 0) {
            float4 c4 = *(const float4*)(cvec + r * 4);
            float4 o = { p0 + c4.x, p1 + c4.y, p2 + c4.z, p3 + c4.w };
            *(float4*)(er + ((size_t)r * N_NODES + n) * 4) = o;
        }
    }
}

// ---------------- fused src pipeline v5: 8 waves x (64x32); hs stored bf16 pair-packed -----
#define XPITCH 136   // ushorts/row = 272B: 16B-aligned, dword stride 68 == 4 (mod 32) (conflict-free class)
__global__ __launch_bounds__(512) void fused_src_kernel(
    const float* __restrict__ src_feats, const unsigned short* __restrict__ WtsT,
    const float* __restrict__ bt_src, const unsigned short* __restrict__ WgT,
    const float* __restrict__ attn_l, unsigned short* __restrict__ hs, float* __restrict__ el)
{
    __shared__ unsigned short Xs[128 * XPITCH];   // 34.8 KB: input tile, then srcT tile
    const int r = blockIdx.y;
    const int row0 = blockIdx.x * 128;
    const int t = threadIdx.x, wave = t >> 6, lane = t & 63;
    const int wm = wave >> 2, wc = wave & 3, lm = lane & 15, quad = lane >> 4;
    const float* A = src_feats + (size_t)r * N_NODES * 128;

    // stage input tile fp32->bf16 (8 float4 per thread)
#pragma unroll
    for (int i = 0; i < 8; ++i) {
        int item = t + i * 512;                 // 4096 = 128 rows x 32 float4
        int m = item >> 5, kq = item & 31;
        int gr = row0 + m; gr = gr < N_NODES ? gr : N_NODES - 1;
        float4 v = *(const float4*)(A + (size_t)gr * 128 + kq * 4);
        uint2 u;
        u.x = f2bf(v.x) | (f2bf(v.y) << 16);
        u.y = f2bf(v.z) | (f2bf(v.w) << 16);
        *(uint2*)(&Xs[m * XPITCH + kq * 4]) = u;
    }
    __syncthreads();

    floatx4 acc[4][2];
#pragma unroll
    for (int i = 0; i < 4; ++i)
#pragma unroll
        for (int j = 0; j < 2; ++j) acc[i][j] = (floatx4){0.f, 0.f, 0.f, 0.f};

    // GEMM1: srcT tile = input @ Wt_src^T  (B streamed from L2 per kc)
    const unsigned short* B1 = WtsT + r * 16384;
#pragma unroll
    for (int kc = 0; kc < 4; ++kc) {
        short8 bk[2];
#pragma unroll
        for (int nt = 0; nt < 2; ++nt)
            bk[nt] = *(const short8*)(B1 + (wc * 32 + nt * 16 + lm) * 128 + kc * 32 + quad * 8);
        short8 af[4];
#pragma unroll
        for (int mt = 0; mt < 4; ++mt)
            af[mt] = *(const short8*)(&Xs[(wm * 64 + mt * 16 + lm) * XPITCH + kc * 32 + quad * 8]);
#pragma unroll
        for (int mt = 0; mt < 4; ++mt)
#pragma unroll
            for (int nt = 0; nt < 2; ++nt)
                acc[mt][nt] = __builtin_amdgcn_mfma_f32_16x16x32_bf16(af[mt], bk[nt], acc[mt][nt], 0, 0, 0);
    }
    __syncthreads();   // all Xs (input) reads done

    // repack srcT (+bias) -> bf16 -> Xs (pair-packed via shfl_xor: 4B aligned writes)
#pragma unroll
    for (int mt = 0; mt < 4; ++mt) {
#pragma unroll
        for (int nt = 0; nt < 2; ++nt) {
            const int col = wc * 32 + nt * 16 + lm;
            const float bv = bt_src[r * 128 + col];
#pragma unroll
            for (int rg = 0; rg < 4; ++rg) {
                unsigned mb = f2bf(acc[mt][nt][rg] + bv);
                unsigned pb = (unsigned)__shfl_xor((int)mb, 1);
                if ((lm & 1) == 0) {
                    int trow = wm * 64 + mt * 16 + quad * 4 + rg;
                    *(unsigned*)(&Xs[trow * XPITCH + col]) = mb | (pb << 16);
                }
            }
        }
    }
    __syncthreads();

#pragma unroll
    for (int i = 0; i < 4; ++i)
#pragma unroll
        for (int j = 0; j < 2; ++j) acc[i][j] = (floatx4){0.f, 0.f, 0.f, 0.f};

    // GEMM2: hs tile = srcT @ Wg^T
    const unsigned short* B2 = WgT + r * 16384;
#pragma unroll
    for (int kc = 0; kc < 4; ++kc) {
        short8 bk[2];
#pragma unroll
        for (int nt = 0; nt < 2; ++nt)
            bk[nt] = *(const short8*)(B2 + (wc * 32 + nt * 16 + lm) * 128 + kc * 32 + quad * 8);
        short8 af[4];
#pragma unroll
        for (int mt = 0; mt < 4; ++mt)
            af[mt] = *(const short8*)(&Xs[(wm * 64 + mt * 16 + lm) * XPITCH + kc * 32 + quad * 8]);
#pragma unroll
        for (int mt = 0; mt < 4; ++mt)
#pragma unroll
            for (int nt = 0; nt < 2; ++nt)
                acc[mt][nt] = __builtin_amdgcn_mfma_f32_16x16x32_bf16(af[mt], bk[nt], acc[mt][nt], 0, 0, 0);
    }

    // epilogue: hs (bf16 pair-packed, shfl_xor) + el[row][head]; wave's 32 cols == head wc
    const float* alr = attn_l + r * 128;
    unsigned short* hsr = hs + (size_t)r * N_NODES * 128;
    float* elr = el + (size_t)r * N_NODES * 4;
#pragma unroll
    for (int mt = 0; mt < 4; ++mt) {
        float e4[4] = {0.f, 0.f, 0.f, 0.f};
#pragma unroll
        for (int nt = 0; nt < 2; ++nt) {
            const int col = wc * 32 + nt * 16 + lm;
            const float al = alr[col];
#pragma unroll
            for (int rg = 0; rg < 4; ++rg) {
                int gr = row0 + wm * 64 + mt * 16 + quad * 4 + rg;
                float v = acc[mt][nt][rg];
                unsigned mb = f2bf(v);
                unsigned pb = (unsigned)__shfl_xor((int)mb, 1);
                if ((lm & 1) == 0 && gr < N_NODES)
                    *(unsigned*)(hsr + (size_t)gr * 128 + col) = mb | (pb << 16);
                e4[rg] += v * al;
            }
        }
#pragma unroll
        for (int rg = 0; rg < 4; ++rg) {
            float a = e4[rg];
            a += __shfl_down(a, 8);
            a += __shfl_down(a, 4);
            a += __shfl_down(a, 2);
            a += __shfl_down(a, 1);
            if (lm == 0) {
                int gr = row0 + wm * 64 + mt * 16 + quad * 4 + rg;
                if (gr < N_NODES) elr[(size_t)gr * 4 + wc] = a;
            }
        }
    }
}

// ---------------- fused semantic: T=zr@W1+b1 (regs only) -> partial of sum(tanh(T)*W2) --------
__global__ __launch_bounds__(256) void fused_sem_kernel(
    const float* __restrict__ zr, const unsigned short* __restrict__ W1T,
    const float* __restrict__ b1, const float* __restrict__ W2,
    float* __restrict__ partials)
{
    __shared__ unsigned short Xs[128 * XPITCH];
    const int r = blockIdx.y;
    const int row0 = blockIdx.x * 128;
    const int t = threadIdx.x, wave = t >> 6, lane = t & 63;
    const int wm = wave >> 1, wn = wave & 1, lm = lane & 15, quad = lane >> 4;
    const float* A = zr + (size_t)r * N_NODES * 128;

#pragma unroll
    for (int i = 0; i < 16; ++i) {
        int item = t + i * 256;
        int m = item >> 5, kq = item & 31;
        int gr = row0 + m; gr = gr < N_NODES ? gr : N_NODES - 1;
        float4 v = *(const float4*)(A + (size_t)gr * 128 + kq * 4);
        uint2 u;
        u.x = f2bf(v.x) | (f2bf(v.y) << 16);
        u.y = f2bf(v.z) | (f2bf(v.w) << 16);
        *(uint2*)(&Xs[m * XPITCH + kq * 4]) = u;
    }
    short8 bfrag[4][4];
#pragma unroll
    for (int nt = 0; nt < 4; ++nt)
#pragma unroll
        for (int kc = 0; kc < 4; ++kc)
            bfrag[nt][kc] = *(const short8*)(W1T + (wn * 64 + nt * 16 + lm) * 128 + kc * 32 + quad * 8);
    __syncthreads();

    floatx4 acc[4][4];
#pragma unroll
    for (int i = 0; i < 4; ++i)
#pragma unroll
        for (int j = 0; j < 4; ++j) acc[i][j] = (floatx4){0.f, 0.f, 0.f, 0.f};
#pragma unroll
    for (int kc = 0; kc < 4; ++kc) {
        short8 af[4];
#pragma unroll
        for (int mt = 0; mt < 4; ++mt)
            af[mt] = *(const short8*)(&Xs[(wm * 64 + mt * 16 + lm) * XPITCH + kc * 32 + quad * 8]);
#pragma unroll
        for (int mt = 0; mt < 4; ++mt)
#pragma unroll
            for (int nt = 0; nt < 4; ++nt)
                acc[mt][nt] = __builtin_amdgcn_mfma_f32_16x16x32_bf16(af[mt], bfrag[nt][kc], acc[mt][nt], 0, 0, 0);
    }

    float s = 0.0f;
#pragma unroll
    for (int nt = 0; nt < 4; ++nt) {
        const int col = wn * 64 + nt * 16 + lm;
        const float w2v = W2[col];
        const float b1v = b1[col];
#pragma unroll
        for (int mt = 0; mt < 4; ++mt)
#pragma unroll
            for (int rg = 0; rg < 4; ++rg) {
                int gr = row0 + wm * 64 + mt * 16 + quad * 4 + rg;
                if (gr < N_NODES) s += fast_tanh(acc[mt][nt][rg] + b1v) * w2v;
            }
    }
#pragma unroll
    for (int off = 32; off >= 1; off >>= 1) s += __shfl_down(s, off);
    __shared__ float ws4[4];
    if (lane == 0) ws4[wave] = s;
    __syncthreads();
    if (t == 0) partials[r * GBLK + blockIdx.x] = ws4[0] + ws4[1] + ws4[2] + ws4[3];
}

// ---------------- CSR build ----------------
__global__ void count_kernel(const int* __restrict__ dst_idx, int* __restrict__ counts)
{
    int tid = blockIdx.x * 256 + threadIdx.x;
    if (tid >= R_REL * E_EDGES) return;
    int r = tid / E_EDGES;
    atomicAdd(&counts[r * N_NODES + dst_idx[tid]], 1);
}

__global__ void blocksum_kernel(const int* __restrict__ counts, int* __restrict__ bsums)
{
    int r = blockIdx.y;
    int i = blockIdx.x * 256 + threadIdx.x;
    int v = (i < N_NODES) ? counts[r * N_NODES + i] : 0;
#pragma unroll
    for (int off = 32; off >= 1; off >>= 1) v += __shfl_down(v, off);
    __shared__ int wsum[4];
    int lane = threadIdx.x & 63, w = threadIdx.x >> 6;
    if (lane == 0) wsum[w] = v;
    __syncthreads();
    if (threadIdx.x == 0) bsums[r * NBLK + blockIdx.x] = wsum[0] + wsum[1] + wsum[2] + wsum[3];
}

__global__ void scan_bsums(const int* __restrict__ bsums, int* __restrict__ boffs,
                           int* __restrict__ offs)
{
    int r = blockIdx.x;
    if (threadIdx.x != 0) return;
    int run = 0;
    for (int b = 0; b < NBLK; ++b) { boffs[r * NBLK + b] = run; run += bsums[r * NBLK + b]; }
    offs[r * (N_NODES + 1) + N_NODES] = run;
}

__global__ void scan_final(const int* __restrict__ counts, const int* __restrict__ boffs,
                           int* __restrict__ offs, int* __restrict__ cursor)
{
    int r = blockIdx.y;
    int i = blockIdx.x * 256 + threadIdx.x;
    int t = threadIdx.x;
    int v = (i < N_NODES) ? counts[r * N_NODES + i] : 0;
    __shared__ int sd[256];
    sd[t] = v;
    __syncthreads();
    for (int off = 1; off < 256; off <<= 1) {
        int y = (t >= off) ? sd[t - off] : 0;
        __syncthreads();
        sd[t] += y;
        __syncthreads();
    }
    int excl = sd[t] - v + boffs[r * NBLK + blockIdx.x];
    if (i < N_NODES) {
        offs[r * (N_NODES + 1) + i] = excl;
        cursor[r * N_NODES + i] = excl;
    }
}

// scatter + fused edge logits (softmax shift-invariance: no max subtraction needed, logits O(1))
__global__ void scatter_ex(const int* __restrict__ src_idx, const int* __restrict__ dst_idx,
                           const float* __restrict__ el, const float* __restrict__ er,
                           int* __restrict__ cursor, int* __restrict__ csr_src,
                           float* __restrict__ ex_csr)
{
    int tid = blockIdx.x * 256 + threadIdx.x;
    if (tid >= R_REL * E_EDGES) return;
    int r = tid / E_EDGES;
    int s = src_idx[tid], d = dst_idx[tid];
    float4 a = *(const float4*)(el + ((size_t)r * N_NODES + s) * 4);
    float4 b = *(const float4*)(er + ((size_t)r * N_NODES + d) * 4);
    float e0 = a.x + b.x, e1 = a.y + b.y, e2 = a.z + b.z, e3 = a.w + b.w;
    e0 = e0 > 0.f ? e0 : 0.2f * e0;
    e1 = e1 > 0.f ? e1 : 0.2f * e1;
    e2 = e2 > 0.f ? e2 : 0.2f * e2;
    e3 = e3 > 0.f ? e3 : 0.2f * e3;
    float4 ex = { __expf(e0), __expf(e1), __expf(e2), __expf(e3) };
    int pos = atomicAdd(&cursor[r * N_NODES + d], 1);
    csr_src[(size_t)r * E_EDGES + pos] = s;
    *(float4*)(ex_csr + ((size_t)r * E_EDGES + pos) * 4) = ex;
}

// ---------------- node-centric aggregation v4: v1 skeleton + bf16 hs (half gather bytes) ----
// Back to the proven shuffle-batch structure (R4: 143us, 2.86 TB/s). Lane owns col pair
// (2l, 2l+1), both in head l>>4: ONE 4B uint gather per edge (256B/row coalesced) instead
// of two floats. ex component loaded directly per edge (address known early, L2-hit) ->
// the 16 ex-shuffles per 4-edge group are gone; only 4 index shuffles remain.
__global__ __launch_bounds__(256) void agg_kernel(
    const float* __restrict__ ex_csr, const unsigned short* __restrict__ hs,
    const int* __restrict__ offs, const int* __restrict__ csr_src,
    const float* __restrict__ bias_g, float* __restrict__ zr)
{
    int wid = blockIdx.x * 4 + (threadIdx.x >> 6);
    int r = wid / N_NODES, n = wid - r * N_NODES;
    int lane = threadIdx.x & 63;
    int comp = lane >> 4;          // head for cols 2*lane, 2*lane+1
    int cc = lane * 2;

    int beg = offs[r * (N_NODES + 1) + n];
    int end = offs[r * (N_NODES + 1) + n + 1];
    const int*   srcs = csr_src + (size_t)r * E_EDGES;
    const float* exc  = ex_csr + (size_t)r * E_EDGES * 4;
    const unsigned short* hsr = hs + (size_t)r * N_NODES * HD;

    float ss = 0.f, acc0 = 0.f, acc1 = 0.f;
    for (int base = beg; base < end; base += 64) {
        int j = base + lane;
        int jj = j < end ? j : base;
        int sv = srcs[jj];                       // one coalesced wave-wide index load
        int cnt4 = (min(64, end - base) + 3) & ~3;
        for (int k = 0; k < cnt4; k += 4) {
            int b0 = base + k, b1 = b0 + 1, b2 = b0 + 2, b3 = b0 + 3;
            int s0 = __shfl(sv, k),     s1 = __shfl(sv, k + 1);
            int s2 = __shfl(sv, k + 2), s3 = __shfl(sv, k + 3);
            int j0 = b0 < end ? b0 : beg, j1 = b1 < end ? b1 : beg;
            int j2 = b2 < end ? b2 : beg, j3 = b3 < end ? b3 : beg;
            // per-lane head component, direct loads (independent of gather chain)
            float e0 = exc[(size_t)j0 * 4 + comp];
            float e1 = exc[(size_t)j1 * 4 + comp];
            float e2 = exc[(size_t)j2 * 4 + comp];
            float e3 = exc[(size_t)j3 * 4 + comp];
            // bf16 row gathers: 4B per lane, 256B coalesced per row
            unsigned u0 = *(const unsigned*)(hsr + (size_t)s0 * HD + cc);
            unsigned u1 = *(const unsigned*)(hsr + (size_t)s1 * HD + cc);
            unsigned u2 = *(const unsigned*)(hsr + (size_t)s2 * HD + cc);
            unsigned u3 = *(const unsigned*)(hsr + (size_t)s3 * HD + cc);
            e0 = b0 < end ? e0 : 0.f;
            e1 = b1 < end ? e1 : 0.f;
            e2 = b2 < end ? e2 : 0.f;
            e3 = b3 < end ? e3 : 0.f;
            ss += e0 + e1 + e2 + e3;
            acc0 += e0 * __uint_as_float(u0 << 16) + e1 * __uint_as_float(u1 << 16)
                  + e2 * __uint_as_float(u2 << 16) + e3 * __uint_as_float(u3 << 16);
            acc1 += e0 * __uint_as_float(u0 & 0xffff0000u) + e1 * __uint_as_float(u1 & 0xffff0000u)
                  + e2 * __uint_as_float(u2 & 0xffff0000u) + e3 * __uint_as_float(u3 & 0xffff0000u);
        }
    }
    float r0 = acc0 / (ss + 1e-9f) + bias_g[r * HD + cc];
    float r1 = acc1 / (ss + 1e-9f) + bias_g[r * HD + cc + 1];
    r0 = r0 > 0.0f ? r0 : (__expf(r0) - 1.0f);
    r1 = r1 > 0.0f ? r1 : (__expf(r1) - 1.0f);
    float2 o = { r0, r1 };
    *(float2*)(zr + (size_t)wid * HD + cc) = o;
}

// ---------------- final softmax over relations + combine ----------------
__global__ __launch_bounds__(256) void softmax_a(const float* __restrict__ partials,
                                                 float* __restrict__ a,
                                                 float* __restrict__ out)
{
    __shared__ float sm[3];
    const int t = threadIdx.x;
    if (t < 192) {
        const int r = t >> 6, lane = t & 63;
        float v = 0.0f;
        for (int i = lane; i < GBLK; i += 64) v += partials[r * GBLK + i];
#pragma unroll
        for (int off = 32; off >= 1; off >>= 1) v += __shfl_down(v, off);
        if (lane == 0) sm[r] = v;
    }
    __syncthreads();
    if (t == 0) {
        float w0 = sm[0] / (float)N_NODES;
        float w1 = sm[1] / (float)N_NODES;
        float w2 = sm[2] / (float)N_NODES;
        float m = fmaxf(w0, fmaxf(w1, w2));
        float e0 = __expf(w0 - m), e1 = __expf(w1 - m), e2 = __expf(w2 - m);
        float s = e0 + e1 + e2;
        a[0] = e0 / s; a[1] = e1 / s; a[2] = e2 / s;
        out[(size_t)N_NODES * HD + 0] = a[0];
        out[(size_t)N_NODES * HD + 1] = a[1];
        out[(size_t)N_NODES * HD + 2] = a[2];
    }
}

__global__ __launch_bounds__(256) void combine_kernel(const float* __restrict__ zr,
                                                      const float* __restrict__ a,
                                                      float* __restrict__ out)
{
    size_t i = (size_t)blockIdx.x * 256 + threadIdx.x;
    float a0 = a[0], a1 = a[1], a2 = a[2];
    const float4 v0 = ((const float4*)zr)[i];
    const float4 v1 = ((const float4*)(zr + (size_t)N_NODES * HD))[i];
    const float4 v2 = ((const float4*)(zr + 2 * (size_t)N_NODES * HD))[i];
    float4 o = { a0 * v0.x + a1 * v1.x + a2 * v2.x,
                 a0 * v0.y + a1 * v1.y + a2 * v2.y,
                 a0 * v0.z + a1 * v1.z + a2 * v2.z,
                 a0 * v0.w + a1 * v1.w + a2 * v2.w };
    ((float4*)out)[i] = o;
}

// ---------------- launch ----------------
extern "C" void kernel_launch(void* const* d_in, const int* in_sizes, int n_in,
                              void* d_out, int out_size, void* d_ws, size_t ws_size,
                              hipStream_t stream)
{
    const float* dst_feat  = (const float*)d_in[0];
    const float* src_feats = (const float*)d_in[1];
    const int*   src_idx   = (const int*)d_in[2];
    const int*   dst_idx   = (const int*)d_in[3];
    const float* Wt_dst    = (const float*)d_in[4];
    const float* bt_dst    = (const float*)d_in[5];
    const float* Wt_src    = (const float*)d_in[6];
    const float* bt_src    = (const float*)d_in[7];
    const float* Wg        = (const float*)d_in[8];
    const float* attn_l    = (const float*)d_in[9];
    const float* attn_r    = (const float*)d_in[10];
    const float* bias_g    = (const float*)d_in[11];
    const float* W1        = (const float*)d_in[12];
    const float* b1        = (const float*)d_in[13];
    const float* W2        = (const float*)d_in[14];
    float* out = (float*)d_out;

    char* ws = (char*)d_ws;
    float*          ex_csr = (float*)(ws + OFF_EXCSR);
    unsigned short* WtsT   = (unsigned short*)(ws + OFF_WTS_T);
    unsigned short* WgT    = (unsigned short*)(ws + OFF_WG_T);
    unsigned short* W1T    = (unsigned short*)(ws + OFF_W1_T);
    float*          Mer    = (float*)(ws + OFF_MER);
    float*          cer    = (float*)(ws + OFF_CER);
    float*          parts  = (float*)(ws + OFF_PART);
    float*          zr     = (float*)(ws + OFF_B1);
    unsigned short* hs     = (unsigned short*)(ws + OFF_B2);
    float*          el     = (float*)(ws + OFF_EL);
    float*          er     = (float*)(ws + OFF_ER);
    int*            counts = (int*)(ws + OFF_CNT);
    int*            offs   = (int*)(ws + OFF_OFFS);
    int*            cursor = (int*)(ws + OFF_CUR);
    int*            bsums  = (int*)(ws + OFF_BSUM);
    int*            boffs  = (int*)(ws + OFF_BOFF);
    int*            csr    = (int*)(ws + OFF_CSR);
    float*          abuf   = (float*)(ws + OFF_ABUF);

    hipMemsetAsync(counts, 0, (size_t)R_REL * N_NODES * 4, stream);

    // prep: weight transposes (bf16 [n][k]) + er projection matrix
    transpose_bf16<<<dim3(64, 3), 256, 0, stream>>>(Wt_src, WtsT);
    transpose_bf16<<<dim3(64, 3), 256, 0, stream>>>(Wg, WgT);
    transpose_bf16<<<dim3(64, 1), 256, 0, stream>>>(W1, W1T);
    prep_er<<<3, 512, 0, stream>>>(Wg, attn_r, Wt_dst, bt_dst, Mer, cer);

    // fused src projection chain: hs(bf16) + el
    fused_src_kernel<<<dim3(GBLK, 3), 512, 0, stream>>>(src_feats, WtsT, bt_src, WgT,
                                                        attn_l, hs, el);
    // er directly from dst_feat
    er_direct<<<25000, 256, 0, stream>>>(dst_feat, Mer, cer, er);

    // CSR by dst
    count_kernel<<<3750, 256, 0, stream>>>(dst_idx, counts);
    blocksum_kernel<<<dim3(NBLK, 3), 256, 0, stream>>>(counts, bsums);
    scan_bsums<<<3, 64, 0, stream>>>(bsums, boffs, offs);
    scan_final<<<dim3(NBLK, 3), 256, 0, stream>>>(counts, boffs, offs, cursor);
    scatter_ex<<<3750, 256, 0, stream>>>(src_idx, dst_idx, el, er, cursor, csr, ex_csr);

    // pull aggregation -> zr
    agg_kernel<<<75000, 256, 0, stream>>>(ex_csr, hs, offs, csr, bias_g, zr);

    // fused semantic attention (T never materialized)
    fused_sem_kernel<<<dim3(GBLK, 3), 256, 0, stream>>>(zr, W1T, b1, W2, parts);
    softmax_a<<<1, 256, 0, stream>>>(parts, abuf, out);
    combine_kernel<<<12500, 256, 0, stream>>>(zr, abuf, out);
}

// Round 9
// 699.824 us; speedup vs baseline: 1.1790x; 1.0416x over previous
//
#include <hip/hip_runtime.h>
#include <hip/hip_bf16.h>
#include <math.h>

#define N_NODES 100000
#define R_REL 3
#define E_EDGES 320000
#define HID 128
#define HD 128
#define NBLK 391        // ceil(N/256)
#define GBLK 782        // ceil(N/128)

// ---------------- workspace layout (byte offsets) ----------------
static constexpr size_t OFF_EXCSR = 0;                     // R*E*4 f32 = 15,360,000
static constexpr size_t OFF_WTS_T = 16000000;              // R*128*128 bf16 = 98,304
static constexpr size_t OFF_WG_T  = 16098304;              // R*128*128 bf16 = 98,304
static constexpr size_t OFF_W1_T  = 16196608;              // 128*128 bf16 = 32,768
static constexpr size_t OFF_MER   = 16229376;              // R*128*4 f32 = 6,144
static constexpr size_t OFF_CER   = 16235520;              // R*4 f32 = 48 -> 64
static constexpr size_t OFF_PART  = 16235584;              // R*GBLK f32 = 9,384
static constexpr size_t OFF_B1    = 51200000;              // z_r: R*N*128 f32
static constexpr size_t OFF_B2    = 204800000;             // hs: R*N*128 bf16 (76.8 MB)
static constexpr size_t OFF_EL    = 358400000;             // R*N*4 f32
static constexpr size_t OFF_ER    = 363200000;             // R*N*4 f32
static constexpr size_t OFF_CNT   = 368006144;             // R*N i32
static constexpr size_t OFF_OFFS  = 369206144;             // R*(N+1) i32
static constexpr size_t OFF_CUR   = 370406272;             // R*N i32
static constexpr size_t OFF_BSUM  = 371606272;             // R*NBLK i32
static constexpr size_t OFF_BOFF  = 371611136;             // R*NBLK i32
static constexpr size_t OFF_CSR   = 371616000;             // R*E i32
static constexpr size_t OFF_ABUF  = 375456000;             // 3 f32

typedef __attribute__((ext_vector_type(8))) short short8;
typedef __attribute__((ext_vector_type(4))) float floatx4;

__device__ __forceinline__ unsigned f2bf(float f)
{
    unsigned u = __float_as_uint(f);
    return (u + 0x7FFFu + ((u >> 16) & 1u)) >> 16;   // RNE
}

__device__ __forceinline__ float fast_tanh(float x)
{
    x = fminf(fmaxf(x, -15.0f), 15.0f);
    float e = __expf(2.0f * x);
    return (e - 1.0f) / (e + 1.0f);
}

// ---------------- weight pre-transpose: dst[n][k] = bf16(src[k][n]) ----------------
__global__ void transpose_bf16(const float* __restrict__ src, unsigned short* __restrict__ dst)
{
    int mat = blockIdx.y;
    int idx = blockIdx.x * 256 + threadIdx.x;   // 64 blocks x 256 = 16384
    int n = idx >> 7, k = idx & 127;
    dst[(size_t)mat * 16384 + n * 128 + k] =
        (unsigned short)f2bf(src[(size_t)mat * 16384 + k * 128 + n]);
}

// ---------------- er prep: wr_eff = reduce(Wg,attn_r); M = Wt_dst@wr_eff; c = bt_dst@wr_eff ----
__global__ __launch_bounds__(512) void prep_er(const float* __restrict__ Wg,
                                               const float* __restrict__ attn_r,
                                               const float* __restrict__ Wt_dst,
                                               const float* __restrict__ bt_dst,
                                               float* __restrict__ M, float* __restrict__ cvec)
{
    const int r = blockIdx.x;
    const int t = threadIdx.x;          // 512 = 128 f x 4 h
    const int f = t >> 2, h = t & 3;
    __shared__ float wr[128][4];
    float s = 0.0f;
#pragma unroll
    for (int d = 0; d < 32; ++d)
        s += Wg[(size_t)r * 16384 + f * 128 + h * 32 + d] * attn_r[r * 128 + h * 32 + d];
    wr[f][h] = s;
    __syncthreads();
    float m = 0.0f;
    for (int k = 0; k < 128; ++k) m += Wt_dst[f * 128 + k] * wr[k][h];
    M[((size_t)r * 128 + f) * 4 + h] = m;
    if (f == 0) {
        float c = 0.0f;
        for (int k = 0; k < 128; ++k) c += bt_dst[k] * wr[k][h];
        cvec[r * 4 + h] = c;
    }
}

// ---------------- er_direct: er[r][n][h] = dst_feat[n,:]·M[r][:,h] + c[r][h] ----------------
__global__ __launch_bounds__(256) void er_direct(const float* __restrict__ dst_feat,
                                                 const float* __restrict__ M,
                                                 const float* __restrict__ cvec,
                                                 float* __restrict__ er)
{
    int n = blockIdx.x * 4 + (threadIdx.x >> 6);
    int lane = threadIdx.x & 63;
    float d0 = dst_feat[(size_t)n * 128 + lane];
    float d1 = dst_feat[(size_t)n * 128 + 64 + lane];
#pragma unroll
    for (int r = 0; r < R_REL; ++r) {
        float4 w0 = *(const float4*)(M + ((size_t)r * 128 + lane) * 4);
        float4 w1 = *(const float4*)(M + ((size_t)r * 128 + 64 + lane) * 4);
        float p0 = d0 * w0.x + d1 * w1.x;
        float p1 = d0 * w0.y + d1 * w1.y;
        float p2 = d0 * w0.z + d1 * w1.z;
        float p3 = d0 * w0.w + d1 * w1.w;
#pragma unroll
        for (int off = 32; off >= 1; off >>= 1) {
            p0 += __shfl_down(p0, off);
            p1 += __shfl_down(p1, off);
            p2 += __shfl_down(p2, off);
            p3 += __shfl_down(p3, off);
        }
        if (lane == 0) {
            float4 c4 = *(const float4*)(cvec + r * 4);
            float4 o = { p0 + c4.x, p1 + c4.y, p2 + c4.z, p3 + c4.w };
            *(float4*)(er + ((size_t)r * N_NODES + n) * 4) = o;
        }
    }
}

// ---------------- fused src pipeline v5: 8 waves x (64x32); hs stored bf16 pair-packed -----
#define XPITCH 136   // ushorts/row = 272B: 16B-aligned, dword stride 68 == 4 (mod 32) (conflict-free class)
__global__ __launch_bounds__(512) void fused_src_kernel(
    const float* __restrict__ src_feats, const unsigned short* __restrict__ WtsT,
    const float* __restrict__ bt_src, const unsigned short* __restrict__ WgT,
    const float* __restrict__ attn_l, unsigned short* __restrict__ hs, float* __restrict__ el)
{
    __shared__ unsigned short Xs[128 * XPITCH];   // 34.8 KB: input tile, then srcT tile
    const int r = blockIdx.y;
    const int row0 = blockIdx.x * 128;
    const int t = threadIdx.x, wave = t >> 6, lane = t & 63;
    const int wm = wave >> 2, wc = wave & 3, lm = lane & 15, quad = lane >> 4;
    const float* A = src_feats + (size_t)r * N_NODES * 128;

    // stage input tile fp32->bf16 (8 float4 per thread)
#pragma unroll
    for (int i = 0; i < 8; ++i) {
        int item = t + i * 512;                 // 4096 = 128 rows x 32 float4
        int m = item >> 5, kq = item & 31;
        int gr = row0 + m; gr = gr < N_NODES ? gr : N_NODES - 1;
        float4 v = *(const float4*)(A + (size_t)gr * 128 + kq * 4);
        uint2 u;
        u.x = f2bf(v.x) | (f2bf(v.y) << 16);
        u.y = f2bf(v.z) | (f2bf(v.w) << 16);
        *(uint2*)(&Xs[m * XPITCH + kq * 4]) = u;
    }
    __syncthreads();

    floatx4 acc[4][2];
#pragma unroll
    for (int i = 0; i < 4; ++i)
#pragma unroll
        for (int j = 0; j < 2; ++j) acc[i][j] = (floatx4){0.f, 0.f, 0.f, 0.f};

    // GEMM1: srcT tile = input @ Wt_src^T  (B streamed from L2 per kc)
    const unsigned short* B1 = WtsT + r * 16384;
#pragma unroll
    for (int kc = 0; kc < 4; ++kc) {
        short8 bk[2];
#pragma unroll
        for (int nt = 0; nt < 2; ++nt)
            bk[nt] = *(const short8*)(B1 + (wc * 32 + nt * 16 + lm) * 128 + kc * 32 + quad * 8);
        short8 af[4];
#pragma unroll
        for (int mt = 0; mt < 4; ++mt)
            af[mt] = *(const short8*)(&Xs[(wm * 64 + mt * 16 + lm) * XPITCH + kc * 32 + quad * 8]);
#pragma unroll
        for (int mt = 0; mt < 4; ++mt)
#pragma unroll
            for (int nt = 0; nt < 2; ++nt)
                acc[mt][nt] = __builtin_amdgcn_mfma_f32_16x16x32_bf16(af[mt], bk[nt], acc[mt][nt], 0, 0, 0);
    }
    __syncthreads();   // all Xs (input) reads done

    // repack srcT (+bias) -> bf16 -> Xs (pair-packed via shfl_xor: 4B aligned writes)
#pragma unroll
    for (int mt = 0; mt < 4; ++mt) {
#pragma unroll
        for (int nt = 0; nt < 2; ++nt) {
            const int col = wc * 32 + nt * 16 + lm;
            const float bv = bt_src[r * 128 + col];
#pragma unroll
            for (int rg = 0; rg < 4; ++rg) {
                unsigned mb = f2bf(acc[mt][nt][rg] + bv);
                unsigned pb = (unsigned)__shfl_xor((int)mb, 1);
                if ((lm & 1) == 0) {
                    int trow = wm * 64 + mt * 16 + quad * 4 + rg;
                    *(unsigned*)(&Xs[trow * XPITCH + col]) = mb | (pb << 16);
                }
            }
        }
    }
    __syncthreads();

#pragma unroll
    for (int i = 0; i < 4; ++i)
#pragma unroll
        for (int j = 0; j < 2; ++j) acc[i][j] = (floatx4){0.f, 0.f, 0.f, 0.f};

    // GEMM2: hs tile = srcT @ Wg^T
    const unsigned short* B2 = WgT + r * 16384;
#pragma unroll
    for (int kc = 0; kc < 4; ++kc) {
        short8 bk[2];
#pragma unroll
        for (int nt = 0; nt < 2; ++nt)
            bk[nt] = *(const short8*)(B2 + (wc * 32 + nt * 16 + lm) * 128 + kc * 32 + quad * 8);
        short8 af[4];
#pragma unroll
        for (int mt = 0; mt < 4; ++mt)
            af[mt] = *(const short8*)(&Xs[(wm * 64 + mt * 16 + lm) * XPITCH + kc * 32 + quad * 8]);
#pragma unroll
        for (int mt = 0; mt < 4; ++mt)
#pragma unroll
            for (int nt = 0; nt < 2; ++nt)
                acc[mt][nt] = __builtin_amdgcn_mfma_f32_16x16x32_bf16(af[mt], bk[nt], acc[mt][nt], 0, 0, 0);
    }

    // epilogue: hs (bf16 pair-packed, shfl_xor) + el[row][head]; wave's 32 cols == head wc
    const float* alr = attn_l + r * 128;
    unsigned short* hsr = hs + (size_t)r * N_NODES * 128;
    float* elr = el + (size_t)r * N_NODES * 4;
#pragma unroll
    for (int mt = 0; mt < 4; ++mt) {
        float e4[4] = {0.f, 0.f, 0.f, 0.f};
#pragma unroll
        for (int nt = 0; nt < 2; ++nt) {
            const int col = wc * 32 + nt * 16 + lm;
            const float al = alr[col];
#pragma unroll
            for (int rg = 0; rg < 4; ++rg) {
                int gr = row0 + wm * 64 + mt * 16 + quad * 4 + rg;
                float v = acc[mt][nt][rg];
                unsigned mb = f2bf(v);
                unsigned pb = (unsigned)__shfl_xor((int)mb, 1);
                if ((lm & 1) == 0 && gr < N_NODES)
                    *(unsigned*)(hsr + (size_t)gr * 128 + col) = mb | (pb << 16);
                e4[rg] += v * al;
            }
        }
#pragma unroll
        for (int rg = 0; rg < 4; ++rg) {
            float a = e4[rg];
            a += __shfl_down(a, 8);
            a += __shfl_down(a, 4);
            a += __shfl_down(a, 2);
            a += __shfl_down(a, 1);
            if (lm == 0) {
                int gr = row0 + wm * 64 + mt * 16 + quad * 4 + rg;
                if (gr < N_NODES) elr[(size_t)gr * 4 + wc] = a;
            }
        }
    }
}

// ---------------- fused semantic: T=zr@W1+b1 (regs only) -> partial of sum(tanh(T)*W2) --------
__global__ __launch_bounds__(256) void fused_sem_kernel(
    const float* __restrict__ zr, const unsigned short* __restrict__ W1T,
    const float* __restrict__ b1, const float* __restrict__ W2,
    float* __restrict__ partials)
{
    __shared__ unsigned short Xs[128 * XPITCH];
    const int r = blockIdx.y;
    const int row0 = blockIdx.x * 128;
    const int t = threadIdx.x, wave = t >> 6, lane = t & 63;
    const int wm = wave >> 1, wn = wave & 1, lm = lane & 15, quad = lane >> 4;
    const float* A = zr + (size_t)r * N_NODES * 128;

#pragma unroll
    for (int i = 0; i < 16; ++i) {
        int item = t + i * 256;
        int m = item >> 5, kq = item & 31;
        int gr = row0 + m; gr = gr < N_NODES ? gr : N_NODES - 1;
        float4 v = *(const float4*)(A + (size_t)gr * 128 + kq * 4);
        uint2 u;
        u.x = f2bf(v.x) | (f2bf(v.y) << 16);
        u.y = f2bf(v.z) | (f2bf(v.w) << 16);
        *(uint2*)(&Xs[m * XPITCH + kq * 4]) = u;
    }
    short8 bfrag[4][4];
#pragma unroll
    for (int nt = 0; nt < 4; ++nt)
#pragma unroll
        for (int kc = 0; kc < 4; ++kc)
            bfrag[nt][kc] = *(const short8*)(W1T + (wn * 64 + nt * 16 + lm) * 128 + kc * 32 + quad * 8);
    __syncthreads();

    floatx4 acc[4][4];
#pragma unroll
    for (int i = 0; i < 4; ++i)
#pragma unroll
        for (int j = 0; j < 4; ++j) acc[i][j] = (floatx4){0.f, 0.f, 0.f, 0.f};
#pragma unroll
    for (int kc = 0; kc < 4; ++kc) {
        short8 af[4];
#pragma unroll
        for (int mt = 0; mt < 4; ++mt)
            af[mt] = *(const short8*)(&Xs[(wm * 64 + mt * 16 + lm) * XPITCH + kc * 32 + quad * 8]);
#pragma unroll
        for (int mt = 0; mt < 4; ++mt)
#pragma unroll
            for (int nt = 0; nt < 4; ++nt)
                acc[mt][nt] = __builtin_amdgcn_mfma_f32_16x16x32_bf16(af[mt], bfrag[nt][kc], acc[mt][nt], 0, 0, 0);
    }

    float s = 0.0f;
#pragma unroll
    for (int nt = 0; nt < 4; ++nt) {
        const int col = wn * 64 + nt * 16 + lm;
        const float w2v = W2[col];
        const float b1v = b1[col];
#pragma unroll
        for (int mt = 0; mt < 4; ++mt)
#pragma unroll
            for (int rg = 0; rg < 4; ++rg) {
                int gr = row0 + wm * 64 + mt * 16 + quad * 4 + rg;
                if (gr < N_NODES) s += fast_tanh(acc[mt][nt][rg] + b1v) * w2v;
            }
    }
#pragma unroll
    for (int off = 32; off >= 1; off >>= 1) s += __shfl_down(s, off);
    __shared__ float ws4[4];
    if (lane == 0) ws4[wave] = s;
    __syncthreads();
    if (t == 0) partials[r * GBLK + blockIdx.x] = ws4[0] + ws4[1] + ws4[2] + ws4[3];
}

// ---------------- CSR build ----------------
__global__ void count_kernel(const int* __restrict__ dst_idx, int* __restrict__ counts)
{
    int tid = blockIdx.x * 256 + threadIdx.x;
    if (tid >= R_REL * E_EDGES) return;
    int r = tid / E_EDGES;
    atomicAdd(&counts[r * N_NODES + dst_idx[tid]], 1);
}

__global__ void blocksum_kernel(const int* __restrict__ counts, int* __restrict__ bsums)
{
    int r = blockIdx.y;
    int i = blockIdx.x * 256 + threadIdx.x;
    int v = (i < N_NODES) ? counts[r * N_NODES + i] : 0;
#pragma unroll
    for (int off = 32; off >= 1; off >>= 1) v += __shfl_down(v, off);
    __shared__ int wsum[4];
    int lane = threadIdx.x & 63, w = threadIdx.x >> 6;
    if (lane == 0) wsum[w] = v;
    __syncthreads();
    if (threadIdx.x == 0) bsums[r * NBLK + blockIdx.x] = wsum[0] + wsum[1] + wsum[2] + wsum[3];
}

__global__ void scan_bsums(const int* __restrict__ bsums, int* __restrict__ boffs,
                           int* __restrict__ offs)
{
    int r = blockIdx.x;
    if (threadIdx.x != 0) return;
    int run = 0;
    for (int b = 0; b < NBLK; ++b) { boffs[r * NBLK + b] = run; run += bsums[r * NBLK + b]; }
    offs[r * (N_NODES + 1) + N_NODES] = run;
}

__global__ void scan_final(const int* __restrict__ counts, const int* __restrict__ boffs,
                           int* __restrict__ offs, int* __restrict__ cursor)
{
    int r = blockIdx.y;
    int i = blockIdx.x * 256 + threadIdx.x;
    int t = threadIdx.x;
    int v = (i < N_NODES) ? counts[r * N_NODES + i] : 0;
    __shared__ int sd[256];
    sd[t] = v;
    __syncthreads();
    for (int off = 1; off < 256; off <<= 1) {
        int y = (t >= off) ? sd[t - off] : 0;
        __syncthreads();
        sd[t] += y;
        __syncthreads();
    }
    int excl = sd[t] - v + boffs[r * NBLK + blockIdx.x];
    if (i < N_NODES) {
        offs[r * (N_NODES + 1) + i] = excl;
        cursor[r * N_NODES + i] = excl;
    }
}

// scatter + fused edge logits (softmax shift-invariance: no max subtraction needed, logits O(1))
__global__ void scatter_ex(const int* __restrict__ src_idx, const int* __restrict__ dst_idx,
                           const float* __restrict__ el, const float* __restrict__ er,
                           int* __restrict__ cursor, int* __restrict__ csr_src,
                           float* __restrict__ ex_csr)
{
    int tid = blockIdx.x * 256 + threadIdx.x;
    if (tid >= R_REL * E_EDGES) return;
    int r = tid / E_EDGES;
    int s = src_idx[tid], d = dst_idx[tid];
    float4 a = *(const float4*)(el + ((size_t)r * N_NODES + s) * 4);
    float4 b = *(const float4*)(er + ((size_t)r * N_NODES + d) * 4);
    float e0 = a.x + b.x, e1 = a.y + b.y, e2 = a.z + b.z, e3 = a.w + b.w;
    e0 = e0 > 0.f ? e0 : 0.2f * e0;
    e1 = e1 > 0.f ? e1 : 0.2f * e1;
    e2 = e2 > 0.f ? e2 : 0.2f * e2;
    e3 = e3 > 0.f ? e3 : 0.2f * e3;
    float4 ex = { __expf(e0), __expf(e1), __expf(e2), __expf(e3) };
    int pos = atomicAdd(&cursor[r * N_NODES + d], 1);
    csr_src[(size_t)r * E_EDGES + pos] = s;
    *(float4*)(ex_csr + ((size_t)r * E_EDGES + pos) * 4) = ex;
}

// ---------------- node-centric aggregation v5: 2 nodes/wave, 32 lanes x 4 cols each ---------
// v4 post-mortem: traffic near floor, VALUBusy 68% -> per-edge/per-node instruction overhead
// is the limiter. Keep v4's proven patterns (coalesced index load + bpermute broadcast +
// direct per-lane ex loads + bf16 gathers) but serve 2 nodes per wave: shared overhead
// (shuffles, clamps, ex addrs, loop control, prologue/epilogue) paid once per node-PAIR;
// lockstep cost E[max(d1,d2)] ~ 4.1 vs E[d1+d2] = 6.4. Adjacent nodes' CSR ranges are
// contiguous -> the two halves' 32-wide index loads form one contiguous segment.
__global__ __launch_bounds__(256) void agg_kernel(
    const float* __restrict__ ex_csr, const unsigned short* __restrict__ hs,
    const int* __restrict__ offs, const int* __restrict__ csr_src,
    const float* __restrict__ bias_g, float* __restrict__ zr)
{
    const int lane = threadIdx.x & 63;
    const int half = lane >> 5;                  // which node of the pair
    const int sl = lane & 31;                    // lane within node group
    const int g = blockIdx.x * 8 + (threadIdx.x >> 6) * 2 + half;   // global (r,n) id
    const int r = g / N_NODES, n = g - r * N_NODES;
    const int comp = sl >> 3;                    // head for cols 4sl..4sl+3
    const int cc = sl * 4;

    const int beg = offs[r * (N_NODES + 1) + n];
    const int end = offs[r * (N_NODES + 1) + n + 1];
    const int*   srcs = csr_src + (size_t)r * E_EDGES;
    const float* exc  = ex_csr + (size_t)r * E_EDGES * 4;
    const unsigned short* hsr = hs + (size_t)r * N_NODES * HD;
    const int L = lane & 32;                     // shuffle base lane for this half

    float ss = 0.f, a0 = 0.f, a1 = 0.f, a2 = 0.f, a3 = 0.f;
    for (int base = beg; base < end; base += 32) {
        int j = base + sl;
        int jj = j < end ? j : base;
        int sv = srcs[jj];                       // contiguous index load across both halves
        int cnt4 = (min(32, end - base) + 3) & ~3;
        for (int k = 0; k < cnt4; k += 4) {
            int b0 = base + k, b1 = b0 + 1, b2 = b0 + 2, b3 = b0 + 3;
            int s0 = __shfl(sv, L + k),     s1 = __shfl(sv, L + k + 1);
            int s2 = __shfl(sv, L + k + 2), s3 = __shfl(sv, L + k + 3);
            int j0 = b0 < end ? b0 : beg, j1 = b1 < end ? b1 : beg;
            int j2 = b2 < end ? b2 : beg, j3 = b3 < end ? b3 : beg;
            // per-lane head component, direct loads (independent of gather chain)
            float e0 = exc[(size_t)j0 * 4 + comp];
            float e1 = exc[(size_t)j1 * 4 + comp];
            float e2 = exc[(size_t)j2 * 4 + comp];
            float e3 = exc[(size_t)j3 * 4 + comp];
            // bf16 row gathers: 8B per lane, 256B coalesced per row, 2 rows per wave-inst
            uint2 q0 = *(const uint2*)(hsr + (size_t)s0 * HD + cc);
            uint2 q1 = *(const uint2*)(hsr + (size_t)s1 * HD + cc);
            uint2 q2 = *(const uint2*)(hsr + (size_t)s2 * HD + cc);
            uint2 q3 = *(const uint2*)(hsr + (size_t)s3 * HD + cc);
            e0 = b0 < end ? e0 : 0.f;
            e1 = b1 < end ? e1 : 0.f;
            e2 = b2 < end ? e2 : 0.f;
            e3 = b3 < end ? e3 : 0.f;
            ss += e0 + e1 + e2 + e3;
            a0 += e0 * __uint_as_float(q0.x << 16) + e1 * __uint_as_float(q1.x << 16)
                + e2 * __uint_as_float(q2.x << 16) + e3 * __uint_as_float(q3.x << 16);
            a1 += e0 * __uint_as_float(q0.x & 0xffff0000u) + e1 * __uint_as_float(q1.x & 0xffff0000u)
                + e2 * __uint_as_float(q2.x & 0xffff0000u) + e3 * __uint_as_float(q3.x & 0xffff0000u);
            a2 += e0 * __uint_as_float(q0.y << 16) + e1 * __uint_as_float(q1.y << 16)
                + e2 * __uint_as_float(q2.y << 16) + e3 * __uint_as_float(q3.y << 16);
            a3 += e0 * __uint_as_float(q0.y & 0xffff0000u) + e1 * __uint_as_float(q1.y & 0xffff0000u)
                + e2 * __uint_as_float(q2.y & 0xffff0000u) + e3 * __uint_as_float(q3.y & 0xffff0000u);
        }
    }
    float inv = 1.0f / (ss + 1e-9f);
    float4 bg = *(const float4*)(bias_g + r * HD + cc);
    float r0 = a0 * inv + bg.x;
    float r1 = a1 * inv + bg.y;
    float r2 = a2 * inv + bg.z;
    float r3 = a3 * inv + bg.w;
    r0 = r0 > 0.0f ? r0 : (__expf(r0) - 1.0f);
    r1 = r1 > 0.0f ? r1 : (__expf(r1) - 1.0f);
    r2 = r2 > 0.0f ? r2 : (__expf(r2) - 1.0f);
    r3 = r3 > 0.0f ? r3 : (__expf(r3) - 1.0f);
    float4 o = { r0, r1, r2, r3 };
    *(float4*)(zr + (size_t)g * HD + cc) = o;
}

// ---------------- final softmax over relations + combine ----------------
__global__ __launch_bounds__(256) void softmax_a(const float* __restrict__ partials,
                                                 float* __restrict__ a,
                                                 float* __restrict__ out)
{
    __shared__ float sm[3];
    const int t = threadIdx.x;
    if (t < 192) {
        const int r = t >> 6, lane = t & 63;
        float v = 0.0f;
        for (int i = lane; i < GBLK; i += 64) v += partials[r * GBLK + i];
#pragma unroll
        for (int off = 32; off >= 1; off >>= 1) v += __shfl_down(v, off);
        if (lane == 0) sm[r] = v;
    }
    __syncthreads();
    if (t == 0) {
        float w0 = sm[0] / (float)N_NODES;
        float w1 = sm[1] / (float)N_NODES;
        float w2 = sm[2] / (float)N_NODES;
        float m = fmaxf(w0, fmaxf(w1, w2));
        float e0 = __expf(w0 - m), e1 = __expf(w1 - m), e2 = __expf(w2 - m);
        float s = e0 + e1 + e2;
        a[0] = e0 / s; a[1] = e1 / s; a[2] = e2 / s;
        out[(size_t)N_NODES * HD + 0] = a[0];
        out[(size_t)N_NODES * HD + 1] = a[1];
        out[(size_t)N_NODES * HD + 2] = a[2];
    }
}

__global__ __launch_bounds__(256) void combine_kernel(const float* __restrict__ zr,
                                                      const float* __restrict__ a,
                                                      float* __restrict__ out)
{
    size_t i = (size_t)blockIdx.x * 256 + threadIdx.x;
    float a0 = a[0], a1 = a[1], a2 = a[2];
    const float4 v0 = ((const float4*)zr)[i];
    const float4 v1 = ((const float4*)(zr + (size_t)N_NODES * HD))[i];
    const float4 v2 = ((const float4*)(zr + 2 * (size_t)N_NODES * HD))[i];
    float4 o = { a0 * v0.x + a1 * v1.x + a2 * v2.x,
                 a0 * v0.y + a1 * v1.y + a2 * v2.y,
                 a0 * v0.z + a1 * v1.z + a2 * v2.z,
                 a0 * v0.w + a1 * v1.w + a2 * v2.w };
    ((float4*)out)[i] = o;
}

// ---------------- launch ----------------
extern "C" void kernel_launch(void* const* d_in, const int* in_sizes, int n_in,
                              void* d_out, int out_size, void* d_ws, size_t ws_size,
                              hipStream_t stream)
{
    const float* dst_feat  = (const float*)d_in[0];
    const float* src_feats = (const float*)d_in[1];
    const int*   src_idx   = (const int*)d_in[2];
    const int*   dst_idx   = (const int*)d_in[3];
    const float* Wt_dst    = (const float*)d_in[4];
    const float* bt_dst    = (const float*)d_in[5];
    const float* Wt_src    = (const float*)d_in[6];
    const float* bt_src    = (const float*)d_in[7];
    const float* Wg        = (const float*)d_in[8];
    const float* attn_l    = (const float*)d_in[9];
    const float* attn_r    = (const float*)d_in[10];
    const float* bias_g    = (const float*)d_in[11];
    const float* W1        = (const float*)d_in[12];
    const float* b1        = (const float*)d_in[13];
    const float* W2        = (const float*)d_in[14];
    float* out = (float*)d_out;

    char* ws = (char*)d_ws;
    float*          ex_csr = (float*)(ws + OFF_EXCSR);
    unsigned short* WtsT   = (unsigned short*)(ws + OFF_WTS_T);
    unsigned short* WgT    = (unsigned short*)(ws + OFF_WG_T);
    unsigned short* W1T    = (unsigned short*)(ws + OFF_W1_T);
    float*          Mer    = (float*)(ws + OFF_MER);
    float*          cer    = (float*)(ws + OFF_CER);
    float*          parts  = (float*)(ws + OFF_PART);
    float*          zr     = (float*)(ws + OFF_B1);
    unsigned short* hs     = (unsigned short*)(ws + OFF_B2);
    float*          el     = (float*)(ws + OFF_EL);
    float*          er     = (float*)(ws + OFF_ER);
    int*            counts = (int*)(ws + OFF_CNT);
    int*            offs   = (int*)(ws + OFF_OFFS);
    int*            cursor = (int*)(ws + OFF_CUR);
    int*            bsums  = (int*)(ws + OFF_BSUM);
    int*            boffs  = (int*)(ws + OFF_BOFF);
    int*            csr    = (int*)(ws + OFF_CSR);
    float*          abuf   = (float*)(ws + OFF_ABUF);

    hipMemsetAsync(counts, 0, (size_t)R_REL * N_NODES * 4, stream);

    // prep: weight transposes (bf16 [n][k]) + er projection matrix
    transpose_bf16<<<dim3(64, 3), 256, 0, stream>>>(Wt_src, WtsT);
    transpose_bf16<<<dim3(64, 3), 256, 0, stream>>>(Wg, WgT);
    transpose_bf16<<<dim3(64, 1), 256, 0, stream>>>(W1, W1T);
    prep_er<<<3, 512, 0, stream>>>(Wg, attn_r, Wt_dst, bt_dst, Mer, cer);

    // fused src projection chain: hs(bf16) + el
    fused_src_kernel<<<dim3(GBLK, 3), 512, 0, stream>>>(src_feats, WtsT, bt_src, WgT,
                                                        attn_l, hs, el);
    // er directly from dst_feat
    er_direct<<<25000, 256, 0, stream>>>(dst_feat, Mer, cer, er);

    // CSR by dst
    count_kernel<<<3750, 256, 0, stream>>>(dst_idx, counts);
    blocksum_kernel<<<dim3(NBLK, 3), 256, 0, stream>>>(counts, bsums);
    scan_bsums<<<3, 64, 0, stream>>>(bsums, boffs, offs);
    scan_final<<<dim3(NBLK, 3), 256, 0, stream>>>(counts, boffs, offs, cursor);
    scatter_ex<<<3750, 256, 0, stream>>>(src_idx, dst_idx, el, er, cursor, csr, ex_csr);

    // pull aggregation -> zr (2 nodes/wave: R*N/8 = 37500 blocks)
    agg_kernel<<<37500, 256, 0, stream>>>(ex_csr, hs, offs, csr, bias_g, zr);

    // fused semantic attention (T never materialized)
    fused_sem_kernel<<<dim3(GBLK, 3), 256, 0, stream>>>(zr, W1T, b1, W2, parts);
    softmax_a<<<1, 256, 0, stream>>>(parts, abuf, out);
    combine_kernel<<<12500, 256, 0, stream>>>(zr, abuf, out);
}